// Round 2
// baseline (879.362 us; speedup 1.0000x reference)
//
#include <hip/hip_runtime.h>

// Problem constants (match reference setup_inputs()).
constexpr int Nn  = 200000;   // nodes
constexpr int Ne  = 3200000;  // edges
constexpr int Ng  = 8192;     // graphs
constexpr int FIN = 28;       // one-hot feature dim
constexpr int DE  = 50;       // embed dim
constexpr int HD  = 16;       // hidden
constexpr int CD  = 2;        // classes

static inline int nblocks(long long n, int bs = 256, int cap = 16384) {
  long long b = (n + bs - 1) / bs;
  return (int)(b < cap ? b : cap);
}

__global__ void k_zero(float* __restrict__ p, int n) {
  int stride = gridDim.x * blockDim.x;
  for (int i = blockIdx.x * blockDim.x + threadIdx.x; i < n; i += stride)
    p[i] = 0.0f;
}

// deg[col[e]] += ea[e]
__global__ void k_deg(const int* __restrict__ col, const float* __restrict__ ea,
                      float* __restrict__ deg, int E) {
  int stride = gridDim.x * blockDim.x;
  for (int e = blockIdx.x * blockDim.x + threadIdx.x; e < E; e += stride)
    atomicAdd(&deg[col[e]], ea[e]);
}

// deg -> dinv = rsqrt(deg + 1) in place (deg+1 >= 1 always)
__global__ void k_dinv(float* __restrict__ deg, int n) {
  int stride = gridDim.x * blockDim.x;
  for (int i = blockIdx.x * blockDim.x + threadIdx.x; i < n; i += stride)
    deg[i] = rsqrtf(deg[i] + 1.0f);
}

// norm[e] = dinv[row]*ea*dinv[col]  (shared by all 3 convs)
__global__ void k_norm(const int* __restrict__ row, const int* __restrict__ col,
                       const float* __restrict__ ea, const float* __restrict__ dinv,
                       float* __restrict__ nrm, int E) {
  int stride = gridDim.x * blockDim.x;
  for (int e = blockIdx.x * blockDim.x + threadIdx.x; e < E; e += stride)
    nrm[e] = dinv[row[e]] * ea[e] * dinv[col[e]];
}

// EW1 = emb @ W1   [28,50]x[50,16] -> [28,16]; one block
__global__ void k_embw(const float* __restrict__ emb, const float* __restrict__ W1,
                       float* __restrict__ EW1) {
  int t = threadIdx.x;
  if (t < FIN * HD) {
    int i = t / HD, k = t % HD;
    float s = 0.0f;
    for (int j = 0; j < DE; ++j) s += emb[i * DE + j] * W1[j * HD + k];
    EW1[t] = s;
  }
}

// hw1[n,:] = EW1[argmax(x[n,:]), :]
__global__ void k_embed(const float* __restrict__ x, const float* __restrict__ EW1,
                        float* __restrict__ hw, int n) {
  int stride = gridDim.x * blockDim.x;
  for (int i = blockIdx.x * blockDim.x + threadIdx.x; i < n; i += stride) {
    const float* xp = x + (long long)i * FIN;
    int arg = 0; float best = xp[0];
#pragma unroll
    for (int j = 1; j < FIN; ++j) { float v = xp[j]; if (v > best) { best = v; arg = j; } }
    const float* ep = EW1 + arg * HD;
#pragma unroll
    for (int k = 0; k < HD; ++k) hw[(long long)i * HD + k] = ep[k];
  }
}

// agg[col[e], k] += hw[row[e], k] * norm[e]; (1<<LOGC) lanes per edge -> coalesced
template <int LOGC>
__global__ void k_scatter(const int* __restrict__ row, const int* __restrict__ col,
                          const float* __restrict__ nrm, const float* __restrict__ hw,
                          float* __restrict__ agg, int E) {
  constexpr int Cw = 1 << LOGC;
  int total = E << LOGC;
  int stride = gridDim.x * blockDim.x;
  for (int i = blockIdx.x * blockDim.x + threadIdx.x; i < total; i += stride) {
    int e = i >> LOGC, k = i & (Cw - 1);
    int r = row[e], c = col[e];
    atomicAdd(&agg[c * Cw + k], hw[r * Cw + k] * nrm[e]);
  }
}

// agg = (relu?)(agg + hw*dinv^2 + b), in place
template <int LOGC, bool RELU>
__global__ void k_selfloop(const float* __restrict__ hw, const float* __restrict__ dinv,
                           const float* __restrict__ b, float* __restrict__ agg, int total) {
  constexpr int Cw = 1 << LOGC;
  int stride = gridDim.x * blockDim.x;
  for (int i = blockIdx.x * blockDim.x + threadIdx.x; i < total; i += stride) {
    int nidx = i >> LOGC, k = i & (Cw - 1);
    float di = dinv[nidx];
    float v = agg[i] + hw[i] * di * di + b[k];
    if (RELU) v = fmaxf(v, 0.0f);
    agg[i] = v;
  }
}

// hw[n,k] = sum_j h[n,j]*W[j,k]  (16 -> 16)
__global__ void k_mm16(const float* __restrict__ h, const float* __restrict__ W,
                       float* __restrict__ hw, int n /* = N*16 */) {
  int stride = gridDim.x * blockDim.x;
  for (int i = blockIdx.x * blockDim.x + threadIdx.x; i < n; i += stride) {
    int nidx = i >> 4, k = i & 15;
    const float* hp = h + (long long)nidx * 16;
    float s = 0.0f;
#pragma unroll
    for (int j = 0; j < 16; ++j) s += hp[j] * W[j * 16 + k];
    hw[i] = s;
  }
}

// hw[n,c] = sum_j h[n,j]*W[j,c]  (16 -> 2)
__global__ void k_mm2(const float* __restrict__ h, const float* __restrict__ W,
                      float* __restrict__ hw, int n /* = N*2 */) {
  int stride = gridDim.x * blockDim.x;
  for (int i = blockIdx.x * blockDim.x + threadIdx.x; i < n; i += stride) {
    int nidx = i >> 1, c = i & 1;
    const float* hp = h + (long long)nidx * 16;
    float s = 0.0f;
#pragma unroll
    for (int j = 0; j < 16; ++j) s += hp[j] * W[j * 2 + c];
    hw[i] = s;
  }
}

__global__ void k_pool(const float* __restrict__ h3, const int* __restrict__ batch,
                       float* __restrict__ sums, float* __restrict__ cnts, int n) {
  int stride = gridDim.x * blockDim.x;
  for (int i = blockIdx.x * blockDim.x + threadIdx.x; i < n; i += stride) {
    int g = batch[i];
    atomicAdd(&sums[g * 2 + 0], h3[(long long)i * 2 + 0]);
    atomicAdd(&sums[g * 2 + 1], h3[(long long)i * 2 + 1]);
    atomicAdd(&cnts[g], 1.0f);
  }
}

__global__ void k_softmax(const float* __restrict__ sums, const float* __restrict__ cnts,
                          float* __restrict__ out, int g) {
  int stride = gridDim.x * blockDim.x;
  for (int i = blockIdx.x * blockDim.x + threadIdx.x; i < g; i += stride) {
    float cnt = fmaxf(cnts[i], 1.0f);
    float c0 = sums[i * 2 + 0] / cnt;
    float c1 = sums[i * 2 + 1] / cnt;
    float m = fmaxf(c0, c1);
    float e0 = __expf(c0 - m), e1 = __expf(c1 - m);
    float inv = 1.0f / (e0 + e1);
    out[i * 2 + 0] = e0 * inv;
    out[i * 2 + 1] = e1 * inv;
  }
}

extern "C" void kernel_launch(void* const* d_in, const int* in_sizes, int n_in,
                              void* d_out, int out_size, void* d_ws, size_t ws_size,
                              hipStream_t stream) {
  const float* x   = (const float*)d_in[0];
  const int*   row = (const int*)d_in[1];
  const int*   col = (const int*)d_in[2];
  const float* ea  = (const float*)d_in[3];
  const int*   bat = (const int*)d_in[4];
  const float* emb = (const float*)d_in[5];
  const float* W1  = (const float*)d_in[6];
  const float* b1  = (const float*)d_in[7];
  const float* W2  = (const float*)d_in[8];
  const float* b2  = (const float*)d_in[9];
  const float* W3  = (const float*)d_in[10];
  const float* b3  = (const float*)d_in[11];
  float* out = (float*)d_out;

  float* ws = (float*)d_ws;
  size_t o = 0;
  float* deg  = ws + o; o += Nn;                 // becomes dinv in place
  float* agg1 = ws + o; o += (size_t)Nn * HD;    // becomes h1 in place
  float* agg2 = ws + o; o += (size_t)Nn * HD;    // becomes h2 in place
  float* agg3 = ws + o; o += (size_t)Nn * CD;    // becomes h3 in place
  float* sums = ws + o; o += (size_t)Ng * CD;
  float* cnts = ws + o; o += Ng;
  size_t zeroN = o;                               // everything above needs 0-init
  float* hw   = ws + o; o += (size_t)Nn * HD;    // hw1 then hw2
  float* hw3  = ws + o; o += (size_t)Nn * CD;
  float* EW1  = ws + o; o += FIN * HD;
  float* nrm  = ws + o; o += Ne;
  (void)ws_size; (void)n_in; (void)in_sizes; (void)out_size;

  const int BS = 256;

  k_zero<<<nblocks(zeroN), BS, 0, stream>>>(ws, (int)zeroN);
  k_deg<<<nblocks(Ne), BS, 0, stream>>>(col, ea, deg, Ne);
  k_dinv<<<nblocks(Nn), BS, 0, stream>>>(deg, Nn);
  k_norm<<<nblocks(Ne), BS, 0, stream>>>(row, col, ea, deg, nrm, Ne);
  k_embw<<<1, 512, 0, stream>>>(emb, W1, EW1);
  k_embed<<<nblocks(Nn), BS, 0, stream>>>(x, EW1, hw, Nn);

  // conv1
  k_scatter<4><<<nblocks((long long)Ne * HD), BS, 0, stream>>>(row, col, nrm, hw, agg1, Ne);
  k_selfloop<4, true><<<nblocks((long long)Nn * HD), BS, 0, stream>>>(hw, deg, b1, agg1, Nn * HD);

  // conv2
  k_mm16<<<nblocks((long long)Nn * HD), BS, 0, stream>>>(agg1, W2, hw, Nn * HD);
  k_scatter<4><<<nblocks((long long)Ne * HD), BS, 0, stream>>>(row, col, nrm, hw, agg2, Ne);
  k_selfloop<4, true><<<nblocks((long long)Nn * HD), BS, 0, stream>>>(hw, deg, b2, agg2, Nn * HD);

  // conv3
  k_mm2<<<nblocks((long long)Nn * CD), BS, 0, stream>>>(agg2, W3, hw3, Nn * CD);
  k_scatter<1><<<nblocks((long long)Ne * CD), BS, 0, stream>>>(row, col, nrm, hw3, agg3, Ne);
  k_selfloop<1, false><<<nblocks((long long)Nn * CD), BS, 0, stream>>>(hw3, deg, b3, agg3, Nn * CD);

  // mean pool + softmax
  k_pool<<<nblocks(Nn), BS, 0, stream>>>(agg3, bat, sums, cnts, Nn);
  k_softmax<<<nblocks(Ng), BS, 0, stream>>>(sums, cnts, out, Ng);
}